// Round 13
// baseline (4292.703 us; speedup 1.0000x reference)
//
#include <hip/hip_runtime.h>
#include <math.h>

// Problem constants
#define DD 256            // latent dim
#define KK 8192           // codebook size
#define NN 16384          // rows
#define NBLOCKS 512       // gather/partial grid (verified 32-row geometry)
#define RSTRIDE 260       // rowsumsq staging stride (unchanged, verified)
#define EPS 2e-3f         // 4x margin over the 5e-4 two-sided approx-error bound
                          // (|err| <= 2^-8 * sum|x*c| ~ 2.5e-4; |c| <= 1/8192)

// Output layout (all float32, concatenated in reference return order)
#define OUT_IDS   0
#define OUT_Q     16384
#define OUT_ST    4210688          // 16384 + 4194304
#define OUT_COMMIT 8404992
#define OUT_CBL    8404993
#define OUT_PERP   8404994

// MFMA fragment types (per guide §3: verified on gfx950)
using bf16x8 = __attribute__((ext_vector_type(8))) short;
using f32x4  = __attribute__((ext_vector_type(4))) float;

// fp32 -> bf16 RNE (finite inputs; bit pattern in ushort)
__device__ __forceinline__ unsigned short f2bf(float f) {
    unsigned u = __float_as_uint(f);
    return (unsigned short)((u + 0x7FFFu + ((u >> 16) & 1u)) >> 16);
}

// ---------------------------------------------------------------------------
// numpy pairwise-sum replica for sum of squares (verified bit-exact)
// ---------------------------------------------------------------------------
__device__ __forceinline__ float np_block128_sumsq(const float* p) {
    #pragma clang fp contract(off)
    float r0 = p[0] * p[0], r1 = p[1] * p[1], r2 = p[2] * p[2], r3 = p[3] * p[3];
    float r4 = p[4] * p[4], r5 = p[5] * p[5], r6 = p[6] * p[6], r7 = p[7] * p[7];
    for (int i = 8; i < 128; i += 8) {
        r0 = r0 + p[i + 0] * p[i + 0];
        r1 = r1 + p[i + 1] * p[i + 1];
        r2 = r2 + p[i + 2] * p[i + 2];
        r3 = r3 + p[i + 3] * p[i + 3];
        r4 = r4 + p[i + 4] * p[i + 4];
        r5 = r5 + p[i + 5] * p[i + 5];
        r6 = r6 + p[i + 6] * p[i + 6];
        r7 = r7 + p[i + 7] * p[i + 7];
    }
    return ((r0 + r1) + (r2 + r3)) + ((r4 + r5) + (r6 + r7));
}

__device__ __forceinline__ float np_pairwise256_sumsq(const float* a) {
    #pragma clang fp contract(off)
    float s0 = np_block128_sumsq(a);
    float s1 = np_block128_sumsq(a + 128);
    return s0 + s1;
}

// ---------------------------------------------------------------------------
// Kernel 1: per-row sum of squares, numpy-pairwise-exact (unchanged, verified)
// ---------------------------------------------------------------------------
__global__ __launch_bounds__(256) void rowsumsq(const float* __restrict__ A,
                                                float* __restrict__ out) {
    __shared__ __align__(16) float sA[64][RSTRIDE];
    const int tid = threadIdx.x;
    const int base = blockIdx.x * 64;
    #pragma unroll
    for (int i = 0; i < 16; ++i) {
        int g = i * 256 + tid;
        int row = g >> 6, d4 = g & 63;
        float4 v = reinterpret_cast<const float4*>(A)[(size_t)(base + row) * (DD / 4) + d4];
        *reinterpret_cast<float4*>(&sA[row][d4 * 4]) = v;
    }
    __syncthreads();
    if (tid < 64) out[base + tid] = np_pairwise256_sumsq(sA[tid]);
}

// ---------------------------------------------------------------------------
// Kernel 1b: fp32 -> bf16 conversion (RNE), vectorized x4. Exact grid.
// ---------------------------------------------------------------------------
__global__ __launch_bounds__(256) void f2bf4(const float4* __restrict__ src,
                                             ushort4* __restrict__ dst) {
    const int i = blockIdx.x * 256 + threadIdx.x;
    float4 v = src[i];
    ushort4 o;
    o.x = f2bf(v.x); o.y = f2bf(v.y); o.z = f2bf(v.z); o.w = f2bf(v.w);
    dst[i] = o;
}

// ---------------------------------------------------------------------------
// Kernel 1c: MFMA layout self-check (1 wave) — verified working in R11/R12.
// On failure (flag=0): minpass2 no-ops and vq_rescan exact-scans ALL chunks
// (bounded parallel, ~460us worst case — correct, never a straggler).
// ---------------------------------------------------------------------------
__global__ void mfma_check(int* __restrict__ flag) {
    const int l = threadIdx.x;          // 64 threads
    bf16x8 a, b;
    #pragma unroll
    for (int i = 0; i < 8; ++i) {
        a[i] = (short)f2bf((float)((l & 15) + 1 + i));
        b[i] = (short)f2bf((float)((l & 15) + 1 + i));
    }
    f32x4 d = {0.f, 0.f, 0.f, 0.f};
    d = __builtin_amdgcn_mfma_f32_16x16x32_bf16(a, b, d, 0, 0, 0);
    bool ok = true;
    #pragma unroll
    for (int j = 0; j < 4; ++j) {
        const int row = (l >> 4) * 4 + j;
        const int col = l & 15;
        float exp = 0.f;
        for (int i = 0; i < 8; ++i)
            exp += (float)((row + 1 + i) * (col + 1 + i));
        exp *= 4.f;
        ok = ok && (d[j] == exp);
    }
    ok = __all(ok);
    if (l == 0) *flag = ok ? 1 : 0;
}

// ---------------------------------------------------------------------------
// Kernel 2: MFMA chunk-min pass — ROUND-13: the ONLY matmul pass (candpass
//   deleted; R12 ran the same 6.87e10-FLOP matmul twice).
//   grid 1024 = 256 row-stripes(64 rows: 4 waves x 16) x 4 col-quarters.
//   ILP fix for R12's 4.4% MfmaUtil (one dependent 8-MFMA chain per tile):
//   process the 4 tiles of each 64-col chunk INTERLEAVED — per kb, 4
//   independent B-loads then 4 independent MFMAs into acc[0..3]. 4 concurrent
//   accumulator chains keep the matrix pipe ~80% fed vs a single chain's ~20%.
//   Output: chunkmin[row][128] = min approx score per (row, 64-col chunk).
//   Epilogue score expr identical to the verified passes: (x2+c2) - 2*acc.
// ---------------------------------------------------------------------------
__global__ __launch_bounds__(256) void mfma_minpass2(const unsigned short* __restrict__ Xb,
                                                     const unsigned short* __restrict__ CBb,
                                                     const float* __restrict__ c2,
                                                     const float* __restrict__ x2,
                                                     float* __restrict__ chunkmin,
                                                     const int* __restrict__ flag) {
    if (*flag == 0) return;
    const int tid = threadIdx.x, lane = tid & 63, wid = tid >> 6;
    const int quarter = blockIdx.x & 3;
    const int rowbase = (blockIdx.x >> 2) * 64 + wid * 16;
    const int colbase0 = quarter * 2048;

    const unsigned short* xrow = Xb + (size_t)(rowbase + (lane & 15)) * DD + (lane >> 4) * 8;
    bf16x8 afr[8];
    #pragma unroll
    for (int kb = 0; kb < 8; ++kb)
        afr[kb] = *reinterpret_cast<const bf16x8*>(xrow + kb * 32);

    float x2r[4];
    #pragma unroll
    for (int j = 0; j < 4; ++j) x2r[j] = x2[rowbase + (lane >> 4) * 4 + j];

    for (int ch = 0; ch < 32; ++ch) {
        const int chunkbase = colbase0 + ch * 64;
        const unsigned short* crow0 = CBb + (size_t)(chunkbase +  0 + (lane & 15)) * DD + (lane >> 4) * 8;
        const unsigned short* crow1 = CBb + (size_t)(chunkbase + 16 + (lane & 15)) * DD + (lane >> 4) * 8;
        const unsigned short* crow2 = CBb + (size_t)(chunkbase + 32 + (lane & 15)) * DD + (lane >> 4) * 8;
        const unsigned short* crow3 = CBb + (size_t)(chunkbase + 48 + (lane & 15)) * DD + (lane >> 4) * 8;
        f32x4 a0 = {0.f, 0.f, 0.f, 0.f}, a1 = a0, a2 = a0, a3 = a0;
        #pragma unroll
        for (int kb = 0; kb < 8; ++kb) {
            bf16x8 b0 = *reinterpret_cast<const bf16x8*>(crow0 + kb * 32);
            bf16x8 b1 = *reinterpret_cast<const bf16x8*>(crow1 + kb * 32);
            bf16x8 b2 = *reinterpret_cast<const bf16x8*>(crow2 + kb * 32);
            bf16x8 b3 = *reinterpret_cast<const bf16x8*>(crow3 + kb * 32);
            a0 = __builtin_amdgcn_mfma_f32_16x16x32_bf16(afr[kb], b0, a0, 0, 0, 0);
            a1 = __builtin_amdgcn_mfma_f32_16x16x32_bf16(afr[kb], b1, a1, 0, 0, 0);
            a2 = __builtin_amdgcn_mfma_f32_16x16x32_bf16(afr[kb], b2, a2, 0, 0, 0);
            a3 = __builtin_amdgcn_mfma_f32_16x16x32_bf16(afr[kb], b3, a3, 0, 0, 0);
        }
        float cmj[4] = {3.4e38f, 3.4e38f, 3.4e38f, 3.4e38f};
        const float c20 = c2[chunkbase +  0 + (lane & 15)];
        const float c21 = c2[chunkbase + 16 + (lane & 15)];
        const float c22 = c2[chunkbase + 32 + (lane & 15)];
        const float c23 = c2[chunkbase + 48 + (lane & 15)];
        #pragma unroll
        for (int j = 0; j < 4; ++j) {
            cmj[j] = fminf(cmj[j], (x2r[j] + c20) - 2.0f * a0[j]);
            cmj[j] = fminf(cmj[j], (x2r[j] + c21) - 2.0f * a1[j]);
            cmj[j] = fminf(cmj[j], (x2r[j] + c22) - 2.0f * a2[j]);
            cmj[j] = fminf(cmj[j], (x2r[j] + c23) - 2.0f * a3[j]);
        }
        #pragma unroll
        for (int j = 0; j < 4; ++j) {
            float m = cmj[j];
            #pragma unroll
            for (int s = 1; s < 16; s <<= 1) m = fminf(m, __shfl_xor(m, s, 64));
            if ((lane & 15) == 0)
                chunkmin[(size_t)(rowbase + (lane >> 4) * 4 + j) * 128
                         + quarter * 32 + ch] = m;
        }
    }
}

// ---------------------------------------------------------------------------
// Kernel 3: exact chunk rescan — replaces candpass + rescore + overflow +
//   unpack. One wave per row: read 128 chunkmins (wave-uniform broadcast),
//   thr = min + EPS; for each qualifying chunk (expected ~15-25), exact
//   fp32 scan of its 64 cols (1 col/lane — VERIFIED chain d=0..255 x/y/z/w,
//   verified score expr), running argmin with first-index ties (ascending
//   chunks + lane tie rule). Guarantee: the exact-min's chunk qualifies
//   (chunkmin_approx <= approx_gmin + 2*bnd <= thr), ties included.
//   flag=0 fallback: scan ALL chunks (bounded parallel, no stragglers).
// ---------------------------------------------------------------------------
__global__ __launch_bounds__(256) void vq_rescan(const float* __restrict__ X,
                                                 const float* __restrict__ CB,
                                                 const float* __restrict__ c2,
                                                 const float* __restrict__ x2,
                                                 const float* __restrict__ mask,
                                                 const float* __restrict__ chunkmin,
                                                 const int* __restrict__ flag,
                                                 float* __restrict__ out,
                                                 float* __restrict__ hist) {
    const int tid = threadIdx.x, lane = tid & 63, wid = tid >> 6;
    const int r = blockIdx.x * 4 + wid;             // 4096 blocks x 4 waves
    const int ok = *flag;
    const float* cm = chunkmin + (size_t)r * 128;

    float thr = 3.4e38f;
    if (ok) {
        float m = fminf(cm[lane], cm[lane + 64]);
        #pragma unroll
        for (int s = 32; s > 0; s >>= 1) m = fminf(m, __shfl_xor(m, s, 64));
        thr = m + EPS;
    }

    const float x2v = x2[r];
    const float4* xv = reinterpret_cast<const float4*>(X + (size_t)r * DD);
    float best = 3.4e38f;
    int besti = 0;

    for (int c = 0; c < 128; ++c) {                 // ascending -> tie order
        if (ok && !(cm[c] <= thr)) continue;        // wave-uniform skip
        const int col = c * 64 + lane;
        const float4* cv = reinterpret_cast<const float4*>(CB + (size_t)col * DD);
        float acc = 0.f;
        #pragma unroll 8
        for (int d4 = 0; d4 < 64; ++d4) {
            float4 a = xv[d4], b = cv[d4];
            acc = fmaf(a.x, b.x, acc);
            acc = fmaf(a.y, b.y, acc);
            acc = fmaf(a.z, b.z, acc);
            acc = fmaf(a.w, b.w, acc);
        }
        float t1 = x2v + c2[col];
        float sc = t1 - 2.0f * acc;
        if (sc < best || (sc == best && col < besti)) { best = sc; besti = col; }
    }
    // wave argmin, first-index ties (verified butterfly)
    #pragma unroll
    for (int m = 32; m > 0; m >>= 1) {
        float b2 = __shfl_xor(best, m, 64);
        int   i2 = __shfl_xor(besti, m, 64);
        if (b2 < best || (b2 == best && i2 < besti)) { best = b2; besti = i2; }
    }
    if (lane == 0) {
        out[OUT_IDS + r] = (float)besti;            // exact integer in float
        atomicAdd(&hist[besti], mask[r]);           // mask=1.0 -> order-exact
    }
}

// ---------------------------------------------------------------------------
// Kernel 4: gather + MSE partials. VERBATIM the verified R0 epilogue ->
//   partial[512] and outq/outst bit-identical. Overwrites ALL scratch
//   (Xb/CBb in OUT_Q; chunkmin/flag in OUT_ST).
// ---------------------------------------------------------------------------
__global__ __launch_bounds__(256) void vq_gather(const float* __restrict__ X,
                                                 const float* __restrict__ CB,
                                                 float* __restrict__ out,
                                                 float* __restrict__ partial) {
    __shared__ int   row_id[32];
    __shared__ float wsum[4];
    const int tid  = threadIdx.x;
    const int lane = tid & 63;
    const int wid  = tid >> 6;
    const int block_row = blockIdx.x * 32;

    if (tid < 32) row_id[tid] = (int)out[OUT_IDS + block_row + tid];
    __syncthreads();

    float msep = 0.0f;
    float* outq  = out + OUT_Q;
    float* outst = out + OUT_ST;
    #pragma unroll
    for (int i = 0; i < 8; ++i) {
        int g2 = i * 256 + tid;         // 0..2047 covers 32 rows x 64 float4
        int row = g2 >> 6;
        int d4  = g2 & 63;
        int id  = row_id[row];
        float4 q = reinterpret_cast<const float4*>(CB)[(size_t)id * (DD / 4) + d4];
        float4 x = reinterpret_cast<const float4*>(X)[(size_t)(block_row + row) * (DD / 4) + d4];
        float4 st;
        st.x = x.x + (q.x - x.x);
        st.y = x.y + (q.y - x.y);
        st.z = x.z + (q.z - x.z);
        st.w = x.w + (q.w - x.w);
        float dx = x.x - q.x; msep = fmaf(dx, dx, msep);
        dx = x.y - q.y; msep = fmaf(dx, dx, msep);
        dx = x.z - q.z; msep = fmaf(dx, dx, msep);
        dx = x.w - q.w; msep = fmaf(dx, dx, msep);
        size_t o = (size_t)(block_row + row) * (DD / 4) + d4;
        reinterpret_cast<float4*>(outq)[o]  = q;
        reinterpret_cast<float4*>(outst)[o] = st;
    }
    #pragma unroll
    for (int off = 32; off > 0; off >>= 1) msep += __shfl_down(msep, off, 64);
    if (lane == 0) wsum[wid] = msep;
    __syncthreads();
    if (tid == 0) partial[blockIdx.x] = wsum[0] + wsum[1] + wsum[2] + wsum[3];
}

// ---------------------------------------------------------------------------
// Kernel 5: finalize losses + perplexity (double precision, single block)
// ---------------------------------------------------------------------------
__global__ __launch_bounds__(256) void vq_finalize(const float* __restrict__ partial,
                                                   const float* __restrict__ hist,
                                                   float* __restrict__ out) {
    __shared__ double red[256];
    const int tid = threadIdx.x;

    double ps = 0.0;
    for (int j = tid; j < NBLOCKS; j += 256) ps += (double)partial[j];
    red[tid] = ps;
    __syncthreads();
    for (int s = 128; s > 0; s >>= 1) {
        if (tid < s) red[tid] += red[tid + s];
        __syncthreads();
    }
    double mse_sum = red[0];
    __syncthreads();

    double hs = 0.0;
    for (int j = tid; j < KK; j += 256) hs += (double)hist[j];
    red[tid] = hs;
    __syncthreads();
    for (int s = 128; s > 0; s >>= 1) {
        if (tid < s) red[tid] += red[tid + s];
        __syncthreads();
    }
    double denom = red[0] > 1.0 ? red[0] : 1.0;
    __syncthreads();

    double ent = 0.0;
    for (int j = tid; j < KK; j += 256) {
        double p = (double)hist[j] / denom;
        ent += p * log(p + 1e-8);
    }
    red[tid] = ent;
    __syncthreads();
    for (int s = 128; s > 0; s >>= 1) {
        if (tid < s) red[tid] += red[tid + s];
        __syncthreads();
    }

    if (tid == 0) {
        double mse = mse_sum / (double)((size_t)NN * DD);
        out[OUT_COMMIT] = (float)(mse * 0.25);
        out[OUT_CBL]    = (float)mse;
        out[OUT_PERP]   = (float)exp(-red[0]);
    }
}

// ---------------------------------------------------------------------------
extern "C" void kernel_launch(void* const* d_in, const int* in_sizes, int n_in,
                              void* d_out, int out_size, void* d_ws, size_t ws_size,
                              hipStream_t stream) {
    const float* latents = (const float*)d_in[0];   // [16,1024,256]
    const float* mask    = (const float*)d_in[1];   // [16,1024]
    const float* cb      = (const float*)d_in[2];   // [8192,256]
    float* out = (float*)d_out;

    // workspace (floats): hist[8192] | partial[512] | c2[8192] | x2[16384]
    float* hist    = (float*)d_ws;
    float* partial = hist + KK;
    float* c2      = partial + NBLOCKS;
    float* x2      = c2 + KK;

    // scratch in the out buffer, all fully overwritten by vq_gather:
    //   OUT_Q region : Xb bf16[NN][DD] + CBb bf16[KK][DD]
    //   OUT_ST region: chunkmin fp32[NN][128] (2,097,152 fl) | flag
    unsigned short* Xb  = (unsigned short*)(out + OUT_Q);
    unsigned short* CBb = (unsigned short*)(out + OUT_Q + 2097152);
    float* chunkmin = out + OUT_ST;
    int*   flag     = (int*)(out + OUT_ST + 2097152);

    hipMemsetAsync(hist, 0, KK * sizeof(float), stream);          // zero histogram
    rowsumsq<<<KK / 64, 256, 0, stream>>>(cb, c2);                 // numpy-exact |c|^2
    rowsumsq<<<NN / 64, 256, 0, stream>>>(latents, x2);            // numpy-exact |x|^2
    f2bf4<<<(NN * DD / 4) / 256, 256, 0, stream>>>(
        (const float4*)latents, (ushort4*)Xb);
    f2bf4<<<(KK * DD / 4) / 256, 256, 0, stream>>>(
        (const float4*)cb, (ushort4*)CBb);
    mfma_check<<<1, 64, 0, stream>>>(flag);
    mfma_minpass2<<<1024, 256, 0, stream>>>(Xb, CBb, c2, x2, chunkmin, flag);
    vq_rescan<<<NN / 4, 256, 0, stream>>>(latents, cb, c2, x2, mask,
                                          chunkmin, flag, out, hist);
    vq_gather<<<NBLOCKS, 256, 0, stream>>>(latents, cb, out, partial);
    vq_finalize<<<1, 256, 0, stream>>>(partial, hist, out);
}